// Round 12
// baseline (110.125 us; speedup 1.0000x reference)
//
#include <hip/hip_runtime.h>
#include <hip/hip_fp16.h>

#define SEQ   80
#define BATCH 32768
#define HID   10

typedef unsigned int uint;
typedef unsigned short ushort;
typedef _Float16 f16;
typedef __attribute__((ext_vector_type(8))) _Float16 f16x8;
typedef __attribute__((ext_vector_type(2))) _Float16 f16x2;
typedef __attribute__((ext_vector_type(2))) __fp16 fp16x2;
typedef __attribute__((ext_vector_type(4))) float f32x4;

#define SIG_SCALE  (-1.44269504f)
#define TANH_SCALE (-2.88539008f)

__device__ __forceinline__ float fast_rcp(float x)  { return __builtin_amdgcn_rcpf(x); }
__device__ __forceinline__ float fast_exp2(float x) { return __builtin_amdgcn_exp2f(x); }
__device__ __forceinline__ float sigp(float a)  { return fast_rcp(1.0f + fast_exp2(a)); }
__device__ __forceinline__ float tanhp(float a) { return 2.0f * fast_rcp(1.0f + fast_exp2(a)) - 1.0f; }
__device__ __forceinline__ float tanh_f(float x){ return tanhp(TANH_SCALE * x); }

union U4V { uint4 u; f16x8 v; };
union UH2 { uint u; f16x2 h; fp16x2 p; };
union HU  { f16 h; ushort s; };

// Single-rcp-merged LSTM cell: 5 exp2 + 2 rcp = 7 trans.
__device__ __forceinline__ float lstm_unit(const f32x4 d, float& c) {
    const float Ei = fast_exp2(d[0]);
    const float Ef = fast_exp2(d[1]);
    const float Eg = fast_exp2(d[2]);
    const float Eo = fast_exp2(d[3]);
    const float Pi = 1.0f + Ei, Pf = 1.0f + Ef, Pg = 1.0f + Eg;
    const float PiPg = Pi * Pg;
    const float R = fast_rcp(PiPg * Pf);
    c = c * (PiPg * R) + ((1.0f - Eg) * Pf) * R;
    const float Ec = fast_exp2(TANH_SCALE * c);
    const float R2 = fast_rcp((1.0f + Eo) * (1.0f + Ec));
    return (1.0f - Ec) * R2;
}

// 6-wave split: per batch-16 group, waves (role,T) = {L0,L1} x {tile0,1,2}.
// Each wave: ONE 16x16x32 MFMA (its 16 gate rows) + ONE lstm_unit per lane
// per step. Per-wave serial chain ~3x shorter than the 2-wave version; ~30
// resident waves/CU (r8-r11 showed time pinned at ~2500 cyc/SIMD-step with
// only ~2.5-4 waves/SIMD: utilization ~60%, stall-bound on the chain).
// Dataflow (identical to r11): triple-buffered LDS rows, body(i): L0 computes
// step i reading buf[(i+2)%3] (h0(i-1) + x(i)), writes h0(i) slots 0-9 of
// buf[i%3]; L1 computes step i-1 reading same buf (h0(i-1), h1(i-2)), writes
// h1(i-1) slots 10-19. Slots 20-39 stay zero forever (L1's k>=20 padding).
__global__ __launch_bounds__(384)
void lstm2_spec6(const float* __restrict__ x, const float* __restrict__ h0in,
                 const float* __restrict__ c0in,
                 const float* __restrict__ Wih0, const float* __restrict__ Whh0,
                 const float* __restrict__ bih0, const float* __restrict__ bhh0,
                 const float* __restrict__ Wih1, const float* __restrict__ Whh1,
                 const float* __restrict__ bih1, const float* __restrict__ bhh1,
                 ushort* __restrict__ y /* f16 bits of h1 (pre-tanh), [T,B,H] */) {
    __shared__ __align__(16) ushort buf[3][16][40];
    const int tid  = threadIdx.x;
    const int l    = tid & 63;
    const int wid  = tid >> 6;      // 0..5
    const int role = wid >= 3;      // 0: layer 0   1: layer 1
    const int T    = wid - role * 3; // tile 0..2
    const int bl   = l & 15;        // batch column
    const int grp  = l >> 4;        // row/k group
    const int u    = 4 * T + grp;   // this lane's unit (>=10 garbage)
    const bool uok = (u < 10);
    const long b   = (long)blockIdx.x * 16 + bl;

    // ---------- A fragment & bias for THIS wave's 16 rows ----------
    f16x8 A;
    f32x4 bs;
    {
        const int R  = 16 * T + bl;
        const int ru = R >> 2, gi = R & 3;
        const bool vr = (R < 40);
        const int tr = gi * 10 + ru;
        const float sc = (gi == 2) ? TANH_SCALE : SIG_SCALE;
#pragma unroll
        for (int j = 0; j < 8; ++j) {
            const int k = grp * 8 + j;
            float w = 0.f;
            if (vr) {
                if (role == 0) {
                    if (k < 10)      w = Whh0[tr * 10 + k];
                    else if (k < 12) w = Wih0[tr * 2 + (k - 10)];
                } else {
                    if (k < 10)      w = Wih1[tr * 10 + k];
                    else if (k < 20) w = Whh1[tr * 10 + (k - 10)];
                }
            }
            A[j] = (f16)(w * sc);
        }
#pragma unroll
        for (int q = 0; q < 4; ++q) {
            const int Rc = 16 * T + grp * 4 + q;   // row of D this lane holds
            const int uc = Rc >> 2, gc = Rc & 3;
            const float scc = (gc == 2) ? TANH_SCALE : SIG_SCALE;
            const int trc = gc * 10 + uc;
            float bb = 0.f;
            if (Rc < 40)
                bb = (role == 0) ? (bih0[trc] + bhh0[trc]) : (bih1[trc] + bhh1[trc]);
            bs[q] = bb * scc;
        }
    }

    // ---------- c state (one unit per lane) ----------
    const size_t cbase = (role == 0) ? 0 : (size_t)BATCH * 10;
    float cS = uok ? c0in[cbase + b * 10 + u] : 0.f;

    // ---------- LDS zero + state seed ----------
    {
        uint* p = (uint*)buf;                    // 3840 B = 960 uints
        for (int idx = tid; idx < 960; idx += 384) p[idx] = 0u;
    }
    __syncthreads();
    if (role == 0) {
        if (uok) { HU h; h.h = (f16)h0in[b * 10 + u]; buf[2][bl][u] = h.s; }
    } else {
        if (uok) { HU h; h.h = (f16)h0in[(size_t)BATCH * 10 + b * 10 + u]; buf[0][bl][10 + u] = h.s; }
    }

    // ---------- pointers & masks ----------
    const float* xq = x + b * 2 + (size_t)BATCH * 2;   // x(1)
    float2 xv = make_float2(0.f, 0.f);
    if (role == 0) xv = *reinterpret_cast<const float2*>(x + b * 2);  // x(0)
    ushort* yq = y + b * HID + u;

    const uint mx  = (grp < 2)  ? 0xFFFFFFFFu : 0u;
    const uint my0 = (grp == 0) ? 0xFFFFFFFFu : 0u;
    const uint sx  = (grp == 1) ? 0xFFFFFFFFu : 0u;

    auto body = [&](int i, ushort (*W)[40], const ushort (*Rb)[40]) {
        __syncthreads();
        if (role == 0) {
            if (i < SEQ) {
                const float2 xnext = *reinterpret_cast<const float2*>(xq);
                U4V r; r.u = *reinterpret_cast<const uint4*>(&Rb[bl][0] + grp * 8);
                UH2 xp; xp.p = __builtin_amdgcn_cvt_pkrtz(xv.x, xv.y);
                U4V bv;
                bv.u.x = r.u.x & mx;
                bv.u.y = (r.u.y & my0) | (xp.u & sx);
                bv.u.z = r.u.z & my0;
                bv.u.w = r.u.w & my0;

                const f32x4 d = __builtin_amdgcn_mfma_f32_16x16x32_f16(A, bv.v, bs, 0, 0, 0);
                HU h; h.h = (f16)lstm_unit(d, cS);
                if (uok) W[bl][u] = h.s;

                xv = xnext;
                if (i + 2 < SEQ) xq += (size_t)BATCH * 2;
            }
        } else {
            if (i >= 1) {
                U4V r; r.u = *reinterpret_cast<const uint4*>(&Rb[bl][0] + grp * 8);

                const f32x4 d = __builtin_amdgcn_mfma_f32_16x16x32_f16(A, r.v, bs, 0, 0, 0);
                HU h; h.h = (f16)lstm_unit(d, cS);
                if (uok) {
                    W[bl][10 + u] = h.s;
                    *yq = h.s;
                }
                yq += (size_t)BATCH * HID;
            }
        }
    };

    // 81 iterations = 27 exact mod-3 groups: (w,r) = (0,2),(1,0),(2,1)
    for (int i0 = 0; i0 < 81; i0 += 3) {
        body(i0 + 0, buf[0], buf[2]);
        body(i0 + 1, buf[1], buf[0]);
        body(i0 + 2, buf[2], buf[1]);
    }
}

// Head as MFMA GEMM over tanh(y), k-split across 2 waves per 16-row group.
// Block: 256 thr = 4 waves = 2 row-groups x 2 k-halves. Halves combined in
// LDS, then each wave emits 20 of the 40 outputs per row.
__global__ __launch_bounds__(256, 2)
void head_mfma(const ushort* __restrict__ yflat, /* f16 bits of h1, [32768][800] */
               const float* __restrict__ W1, const float* __restrict__ b1,
               const float* __restrict__ W2, const float* __restrict__ b2,
               float* __restrict__ out) {
    __shared__ float sbuf[2][2][16][12];
    const int tid  = threadIdx.x;
    const int l    = tid & 63;
    const int wv   = tid >> 6;
    const int rg   = wv >> 1;      // row group 0,1
    const int half = wv & 1;       // k half 0,1
    const int bl   = l & 15;
    const int grp  = l >> 4;
    const long row = ((long)blockIdx.x * 2 + rg) * 16 + bl;

    const ushort* yrow = yflat + row * 800;
    const float* arow = W1 + (size_t)(bl < 10 ? bl : 9) * 800;

    const int c0 = half ? 13 : 0;
    const int c1 = half ? 25 : 13;

    f32x4 acc = {0.f, 0.f, 0.f, 0.f};
    for (int c = c0; c < c1; ++c) {
        U4V bv; bv.u = *reinterpret_cast<const uint4*>(yrow + c * 32 + grp * 8);
        f16x8 tv;
#pragma unroll
        for (int e = 0; e < 8; ++e)
            tv[e] = (f16)tanh_f((float)bv.v[e]);
        const float4 w0 = *reinterpret_cast<const float4*>(arow + c * 32 + grp * 8);
        const float4 w1 = *reinterpret_cast<const float4*>(arow + c * 32 + grp * 8 + 4);
        f16x8 af;
        af[0] = (f16)w0.x; af[1] = (f16)w0.y; af[2] = (f16)w0.z; af[3] = (f16)w0.w;
        af[4] = (f16)w1.x; af[5] = (f16)w1.y; af[6] = (f16)w1.z; af[7] = (f16)w1.w;
        acc = __builtin_amdgcn_mfma_f32_16x16x32_f16(af, tv, acc, 0, 0, 0);
    }

#pragma unroll
    for (int q = 0; q < 4; ++q) {
        const int o = grp * 4 + q;
        if (o < 10)
            sbuf[rg][half][bl][o] = acc[q];
    }
    __syncthreads();

    float s[10];
#pragma unroll
    for (int o = 0; o < 10; ++o)
        s[o] = sigp(SIG_SCALE * (sbuf[rg][0][bl][o] + sbuf[rg][1][bl][o] + b1[o]));

    // this wave emits outputs j = half*20 .. half*20+19; lane picks by grp
    const int jbase = half * 20 + (grp & 1) * 10;   // grp 0,2 -> low 10; 1,3 -> high 10
    float* op = out + row * 40 + jbase;
#pragma unroll
    for (int jj = 0; jj < 10; ++jj) {
        const int j = jbase + jj;
        float r = b2[j];
#pragma unroll
        for (int o = 0; o < 10; ++o) r += s[o] * W2[j * 10 + o];
        op[jj] = r;
    }
}

extern "C" void kernel_launch(void* const* d_in, const int* in_sizes, int n_in,
                              void* d_out, int out_size, void* d_ws, size_t ws_size,
                              hipStream_t stream) {
    const float* x    = (const float*)d_in[0];
    const float* h0   = (const float*)d_in[1];
    const float* c0   = (const float*)d_in[2];
    const float* Wih0 = (const float*)d_in[3];
    const float* Whh0 = (const float*)d_in[4];
    const float* bih0 = (const float*)d_in[5];
    const float* bhh0 = (const float*)d_in[6];
    const float* Wih1 = (const float*)d_in[7];
    const float* Whh1 = (const float*)d_in[8];
    const float* bih1 = (const float*)d_in[9];
    const float* bhh1 = (const float*)d_in[10];
    const float* W1   = (const float*)d_in[11];
    const float* b1   = (const float*)d_in[12];
    const float* W2   = (const float*)d_in[13];
    const float* b2   = (const float*)d_in[14];
    float* out = (float*)d_out;
    ushort* yws = (ushort*)d_ws;  // f16 staging (raw h1), 80*32768*10*2 B

    // one batch-16 group per 384-thread block (6 waves): 2048 blocks
    lstm2_spec6<<<2048, 384, 0, stream>>>(x, h0, c0, Wih0, Whh0, bih0, bhh0,
                                          Wih1, Whh1, bih1, bhh1, yws);
    // 2 row-groups x 2 k-half waves per 256-thread block: 1024 blocks
    head_mfma<<<1024, 256, 0, stream>>>(yws, W1, b1, W2, b2, out);
}

// Round 13
// 93.856 us; speedup vs baseline: 1.1733x; 1.1733x over previous
//
#include <hip/hip_runtime.h>
#include <hip/hip_fp16.h>

#define SEQ   80
#define BATCH 32768
#define HID   10

typedef unsigned int uint;
typedef unsigned short ushort;
typedef _Float16 f16;
typedef __attribute__((ext_vector_type(8))) _Float16 f16x8;
typedef __attribute__((ext_vector_type(2))) _Float16 f16x2;
typedef __attribute__((ext_vector_type(2))) __fp16 fp16x2;
typedef __attribute__((ext_vector_type(4))) float f32x4;

#define SIG_SCALE  (-1.44269504f)
#define TANH_SCALE (-2.88539008f)

__device__ __forceinline__ float fast_rcp(float x)  { return __builtin_amdgcn_rcpf(x); }
__device__ __forceinline__ float fast_exp2(float x) { return __builtin_amdgcn_exp2f(x); }
__device__ __forceinline__ float sigp(float a)  { return fast_rcp(1.0f + fast_exp2(a)); }
__device__ __forceinline__ float tanhp(float a) { return 2.0f * fast_rcp(1.0f + fast_exp2(a)) - 1.0f; }
__device__ __forceinline__ float tanh_f(float x){ return tanhp(TANH_SCALE * x); }

union U4V { uint4 u; f16x8 v; };
union UH2 { uint u; f16x2 h; fp16x2 p; };
union HU  { f16 h; ushort s; };

// Single-rcp-merged LSTM cell: 5 exp2 + 2 rcp = 7 trans.
__device__ __forceinline__ float lstm_unit(const f32x4 d, float& c) {
    const float Ei = fast_exp2(d[0]);
    const float Ef = fast_exp2(d[1]);
    const float Eg = fast_exp2(d[2]);
    const float Eo = fast_exp2(d[3]);
    const float Pi = 1.0f + Ei, Pf = 1.0f + Ef, Pg = 1.0f + Eg;
    const float PiPg = Pi * Pg;
    const float R = fast_rcp(PiPg * Pf);
    c = c * (PiPg * R) + ((1.0f - Eg) * Pf) * R;
    const float Ec = fast_exp2(TANH_SCALE * c);
    const float R2 = fast_rcp((1.0f + Eo) * (1.0f + Ec));
    return (1.0f - Ec) * R2;
}

// Wave-specialized MFMA LSTM — round-11 structure verbatim (best measured:
// 83.4-84.6 us). 128-thread blocks: wave 0 = layer 0 at step i, wave 1 =
// layer 1 at step i-1, triple-buffered LDS rows + 1 barrier/iter; pointer
// bumping; mask-assembled B operand; mod-3 rotation unrolled.
__global__ __launch_bounds__(128, 4)
void lstm2_spec(const float* __restrict__ x, const float* __restrict__ h0in,
                const float* __restrict__ c0in,
                const float* __restrict__ Wih0, const float* __restrict__ Whh0,
                const float* __restrict__ bih0, const float* __restrict__ bhh0,
                const float* __restrict__ Wih1, const float* __restrict__ Whh1,
                const float* __restrict__ bih1, const float* __restrict__ bhh1,
                ushort* __restrict__ y /* f16 bits of h1 (pre-tanh), [T,B,H] */) {
    __shared__ __align__(16) ushort buf[3][16][40];
    const int tid  = threadIdx.x;
    const int l    = tid & 63;
    const int role = tid >> 6;     // 0: layer 0   1: layer 1
    const int bl   = l & 15;       // batch column
    const int grp  = l >> 4;       // row/k group
    const long b   = (long)blockIdx.x * 16 + bl;

    // ---------- A fragment & bias (role-dependent source) ----------
    f16x8 A[3];
    f32x4 bs[3];
#pragma unroll
    for (int T = 0; T < 3; ++T) {
        const int R  = 16 * T + bl;
        const int u  = R >> 2, gi = R & 3;
        const bool vr = (R < 40);
        const int tr = gi * 10 + u;
        const float sc = (gi == 2) ? TANH_SCALE : SIG_SCALE;
#pragma unroll
        for (int j = 0; j < 8; ++j) {
            const int k = grp * 8 + j;
            float w = 0.f;
            if (vr) {
                if (role == 0) {
                    if (k < 10)      w = Whh0[tr * 10 + k];
                    else if (k < 12) w = Wih0[tr * 2 + (k - 10)];
                } else {
                    if (k < 10)      w = Wih1[tr * 10 + k];
                    else if (k < 20) w = Whh1[tr * 10 + (k - 10)];
                }
            }
            A[T][j] = (f16)(w * sc);
        }
#pragma unroll
        for (int q = 0; q < 4; ++q) {
            const int Rc = 16 * T + grp * 4 + q;
            const int uc = Rc >> 2, gc = Rc & 3;
            const float scc = (gc == 2) ? TANH_SCALE : SIG_SCALE;
            const int trc = gc * 10 + uc;
            float bb = 0.f;
            if (Rc < 40)
                bb = (role == 0) ? (bih0[trc] + bhh0[trc]) : (bih1[trc] + bhh1[trc]);
            bs[T][q] = bb * scc;
        }
    }

    // ---------- c state ----------
    const size_t cbase = (role == 0) ? 0 : (size_t)BATCH * 10;
    float cS[3];
#pragma unroll
    for (int T = 0; T < 3; ++T) {
        const int u = 4 * T + grp;
        cS[T] = (u < 10) ? c0in[cbase + b * 10 + u] : 0.f;
    }

    // ---------- LDS zero + state seed ----------
    {
        uint* p = (uint*)buf;                    // 3840 B = 960 uints
        for (int idx = tid; idx < 960; idx += 128) p[idx] = 0u;
    }
    __syncthreads();
    if (role == 0) {
        ushort* row = &buf[2][bl][0];            // read at iter 0
#pragma unroll
        for (int T = 0; T < 3; ++T) {
            const int u = 4 * T + grp;
            if (u < 10) { HU h; h.h = (f16)h0in[b * 10 + u]; row[u] = h.s; }
        }
    } else {
        ushort* row = &buf[0][bl][0];            // read at iter 1
#pragma unroll
        for (int T = 0; T < 3; ++T) {
            const int u = 4 * T + grp;
            if (u < 10) { HU h; h.h = (f16)h0in[(size_t)BATCH * 10 + b * 10 + u]; row[10 + u] = h.s; }
        }
    }

    // ---------- pointers & masks ----------
    const float* xq = x + b * 2 + (size_t)BATCH * 2;   // points at x(1)
    float2 xv = make_float2(0.f, 0.f);
    if (role == 0) xv = *reinterpret_cast<const float2*>(x + b * 2);  // x(0)
    ushort* yq = y + b * HID;

    const uint mx  = (grp < 2)  ? 0xFFFFFFFFu : 0u;
    const uint my0 = (grp == 0) ? 0xFFFFFFFFu : 0u;
    const uint sx  = (grp == 1) ? 0xFFFFFFFFu : 0u;

    auto body = [&](int i, ushort (*W)[40], const ushort (*Rb)[40]) {
        __syncthreads();
        if (role == 0) {
            if (i < SEQ) {
                const float2 xnext = *reinterpret_cast<const float2*>(xq);
                U4V r; r.u = *reinterpret_cast<const uint4*>(&Rb[bl][0] + grp * 8);
                UH2 xp; xp.p = __builtin_amdgcn_cvt_pkrtz(xv.x, xv.y);
                U4V bv;
                bv.u.x = r.u.x & mx;
                bv.u.y = (r.u.y & my0) | (xp.u & sx);
                bv.u.z = r.u.z & my0;
                bv.u.w = r.u.w & my0;

                const f32x4 d0 = __builtin_amdgcn_mfma_f32_16x16x32_f16(A[0], bv.v, bs[0], 0, 0, 0);
                const f32x4 d1 = __builtin_amdgcn_mfma_f32_16x16x32_f16(A[1], bv.v, bs[1], 0, 0, 0);
                const f32x4 d2 = __builtin_amdgcn_mfma_f32_16x16x32_f16(A[2], bv.v, bs[2], 0, 0, 0);

                HU hA; hA.h = (f16)lstm_unit(d0, cS[0]);
                HU hB; hB.h = (f16)lstm_unit(d1, cS[1]);
                HU hC; hC.h = (f16)lstm_unit(d2, cS[2]);

                ushort* wrow = &W[bl][0];
                wrow[grp]     = hA.s;
                wrow[4 + grp] = hB.s;
                if (grp < 2) wrow[8 + grp] = hC.s;

                xv = xnext;
                if (i + 2 < SEQ) xq += (size_t)BATCH * 2;
            }
        } else {
            if (i >= 1) {
                U4V r; r.u = *reinterpret_cast<const uint4*>(&Rb[bl][0] + grp * 8);

                const f32x4 d0 = __builtin_amdgcn_mfma_f32_16x16x32_f16(A[0], r.v, bs[0], 0, 0, 0);
                const f32x4 d1 = __builtin_amdgcn_mfma_f32_16x16x32_f16(A[1], r.v, bs[1], 0, 0, 0);
                const f32x4 d2 = __builtin_amdgcn_mfma_f32_16x16x32_f16(A[2], r.v, bs[2], 0, 0, 0);

                HU hA; hA.h = (f16)lstm_unit(d0, cS[0]);
                HU hB; hB.h = (f16)lstm_unit(d1, cS[1]);
                HU hC; hC.h = (f16)lstm_unit(d2, cS[2]);

                ushort* wrow = &W[bl][0];
                wrow[10 + grp] = hA.s;
                wrow[14 + grp] = hB.s;
                if (grp < 2) wrow[18 + grp] = hC.s;

                yq[grp]     = hA.s;
                yq[4 + grp] = hB.s;
                if (grp < 2) yq[8 + grp] = hC.s;
                yq += (size_t)BATCH * HID;
            }
        }
    };

    // 81 iterations = 27 exact mod-3 groups: (w,r) = (0,2),(1,0),(2,1)
    for (int i0 = 0; i0 < 81; i0 += 3) {
        body(i0 + 0, buf[0], buf[2]);
        body(i0 + 1, buf[1], buf[0]);
        body(i0 + 2, buf[2], buf[1]);
    }
}

// Head as MFMA GEMM over tanh(y), k-split across 2 waves per 16-row group —
// round-12 version verbatim (measured ~8 us).
__global__ __launch_bounds__(256, 2)
void head_mfma(const ushort* __restrict__ yflat, /* f16 bits of h1, [32768][800] */
               const float* __restrict__ W1, const float* __restrict__ b1,
               const float* __restrict__ W2, const float* __restrict__ b2,
               float* __restrict__ out) {
    __shared__ float sbuf[2][2][16][12];
    const int tid  = threadIdx.x;
    const int l    = tid & 63;
    const int wv   = tid >> 6;
    const int rg   = wv >> 1;      // row group 0,1
    const int half = wv & 1;       // k half 0,1
    const int bl   = l & 15;
    const int grp  = l >> 4;
    const long row = ((long)blockIdx.x * 2 + rg) * 16 + bl;

    const ushort* yrow = yflat + row * 800;
    const float* arow = W1 + (size_t)(bl < 10 ? bl : 9) * 800;

    const int c0 = half ? 13 : 0;
    const int c1 = half ? 25 : 13;

    f32x4 acc = {0.f, 0.f, 0.f, 0.f};
    for (int c = c0; c < c1; ++c) {
        U4V bv; bv.u = *reinterpret_cast<const uint4*>(yrow + c * 32 + grp * 8);
        f16x8 tv;
#pragma unroll
        for (int e = 0; e < 8; ++e)
            tv[e] = (f16)tanh_f((float)bv.v[e]);
        const float4 w0 = *reinterpret_cast<const float4*>(arow + c * 32 + grp * 8);
        const float4 w1 = *reinterpret_cast<const float4*>(arow + c * 32 + grp * 8 + 4);
        f16x8 af;
        af[0] = (f16)w0.x; af[1] = (f16)w0.y; af[2] = (f16)w0.z; af[3] = (f16)w0.w;
        af[4] = (f16)w1.x; af[5] = (f16)w1.y; af[6] = (f16)w1.z; af[7] = (f16)w1.w;
        acc = __builtin_amdgcn_mfma_f32_16x16x32_f16(af, tv, acc, 0, 0, 0);
    }

#pragma unroll
    for (int q = 0; q < 4; ++q) {
        const int o = grp * 4 + q;
        if (o < 10)
            sbuf[rg][half][bl][o] = acc[q];
    }
    __syncthreads();

    float s[10];
#pragma unroll
    for (int o = 0; o < 10; ++o)
        s[o] = sigp(SIG_SCALE * (sbuf[rg][0][bl][o] + sbuf[rg][1][bl][o] + b1[o]));

    // this wave emits outputs j = half*20 .. half*20+19; lane picks by grp
    const int jbase = half * 20 + (grp & 1) * 10;
    float* op = out + row * 40 + jbase;
#pragma unroll
    for (int jj = 0; jj < 10; ++jj) {
        const int j = jbase + jj;
        float r = b2[j];
#pragma unroll
        for (int o = 0; o < 10; ++o) r += s[o] * W2[j * 10 + o];
        op[jj] = r;
    }
}

extern "C" void kernel_launch(void* const* d_in, const int* in_sizes, int n_in,
                              void* d_out, int out_size, void* d_ws, size_t ws_size,
                              hipStream_t stream) {
    const float* x    = (const float*)d_in[0];
    const float* h0   = (const float*)d_in[1];
    const float* c0   = (const float*)d_in[2];
    const float* Wih0 = (const float*)d_in[3];
    const float* Whh0 = (const float*)d_in[4];
    const float* bih0 = (const float*)d_in[5];
    const float* bhh0 = (const float*)d_in[6];
    const float* Wih1 = (const float*)d_in[7];
    const float* Whh1 = (const float*)d_in[8];
    const float* bih1 = (const float*)d_in[9];
    const float* bhh1 = (const float*)d_in[10];
    const float* W1   = (const float*)d_in[11];
    const float* b1   = (const float*)d_in[12];
    const float* W2   = (const float*)d_in[13];
    const float* b2   = (const float*)d_in[14];
    float* out = (float*)d_out;
    ushort* yws = (ushort*)d_ws;  // f16 staging (raw h1), 80*32768*10*2 B

    // one batch-16 group per 128-thread block (L0 wave + L1 wave): 2048 blocks
    lstm2_spec<<<2048, 128, 0, stream>>>(x, h0, c0, Wih0, Whh0, bih0, bhh0,
                                         Wih1, Whh1, bih1, bhh1, yws);
    // 2 row-groups x 2 k-half waves per 256-thread block: 1024 blocks
    head_mfma<<<1024, 256, 0, stream>>>(yws, W1, b1, W2, b2, out);
}

// Round 14
// 93.649 us; speedup vs baseline: 1.1759x; 1.0022x over previous
//
#include <hip/hip_runtime.h>
#include <hip/hip_fp16.h>

#define SEQ   80
#define BATCH 32768
#define HID   10

typedef unsigned int uint;
typedef unsigned short ushort;
typedef _Float16 f16;
typedef __attribute__((ext_vector_type(8))) _Float16 f16x8;
typedef __attribute__((ext_vector_type(2))) _Float16 f16x2;
typedef __attribute__((ext_vector_type(2))) __fp16 fp16x2;
typedef __attribute__((ext_vector_type(4))) float f32x4;

#define SIG_SCALE  (-1.44269504f)
#define TANH_SCALE (-2.88539008f)

__device__ __forceinline__ float fast_rcp(float x)  { return __builtin_amdgcn_rcpf(x); }
__device__ __forceinline__ float fast_exp2(float x) { return __builtin_amdgcn_exp2f(x); }
__device__ __forceinline__ float sigp(float a)  { return fast_rcp(1.0f + fast_exp2(a)); }
__device__ __forceinline__ float tanhp(float a) { return 2.0f * fast_rcp(1.0f + fast_exp2(a)) - 1.0f; }
__device__ __forceinline__ float tanh_f(float x){ return tanhp(TANH_SCALE * x); }

// LDS-only barrier: publish our ds_writes (lgkmcnt(0)) then s_barrier, WITHOUT
// the vmcnt(0) drain __syncthreads() emits. The per-iter inter-wave dependency
// is LDS-only; y-stores/x-loads must NOT be drained every step (store-ack is
// ~200-500 cyc). "memory" clobber keeps the compiler from moving LDS ops
// across it.
__device__ __forceinline__ void lds_barrier() {
    asm volatile("s_waitcnt lgkmcnt(0)\n\ts_barrier" ::: "memory");
}

union U4V { uint4 u; f16x8 v; };
union UH2 { uint u; f16x2 h; fp16x2 p; };
union HU  { f16 h; ushort s; };

// Single-rcp-merged LSTM cell: 5 exp2 + 2 rcp = 7 trans.
__device__ __forceinline__ float lstm_unit(const f32x4 d, float& c) {
    const float Ei = fast_exp2(d[0]);
    const float Ef = fast_exp2(d[1]);
    const float Eg = fast_exp2(d[2]);
    const float Eo = fast_exp2(d[3]);
    const float Pi = 1.0f + Ei, Pf = 1.0f + Ef, Pg = 1.0f + Eg;
    const float PiPg = Pi * Pg;
    const float R = fast_rcp(PiPg * Pf);
    c = c * (PiPg * R) + ((1.0f - Eg) * Pf) * R;
    const float Ec = fast_exp2(TANH_SCALE * c);
    const float R2 = fast_rcp((1.0f + Eo) * (1.0f + Ec));
    return (1.0f - Ec) * R2;
}

// Wave-specialized MFMA LSTM — round-11 structure, with the per-iteration
// __syncthreads() replaced by lds_barrier() (no vmcnt drain).
__global__ __launch_bounds__(128, 4)
void lstm2_spec(const float* __restrict__ x, const float* __restrict__ h0in,
                const float* __restrict__ c0in,
                const float* __restrict__ Wih0, const float* __restrict__ Whh0,
                const float* __restrict__ bih0, const float* __restrict__ bhh0,
                const float* __restrict__ Wih1, const float* __restrict__ Whh1,
                const float* __restrict__ bih1, const float* __restrict__ bhh1,
                ushort* __restrict__ y /* f16 bits of h1 (pre-tanh), [T,B,H] */) {
    __shared__ __align__(16) ushort buf[3][16][40];
    const int tid  = threadIdx.x;
    const int l    = tid & 63;
    const int role = tid >> 6;     // 0: layer 0   1: layer 1
    const int bl   = l & 15;       // batch column
    const int grp  = l >> 4;       // row/k group
    const long b   = (long)blockIdx.x * 16 + bl;

    // ---------- A fragment & bias (role-dependent source) ----------
    f16x8 A[3];
    f32x4 bs[3];
#pragma unroll
    for (int T = 0; T < 3; ++T) {
        const int R  = 16 * T + bl;
        const int u  = R >> 2, gi = R & 3;
        const bool vr = (R < 40);
        const int tr = gi * 10 + u;
        const float sc = (gi == 2) ? TANH_SCALE : SIG_SCALE;
#pragma unroll
        for (int j = 0; j < 8; ++j) {
            const int k = grp * 8 + j;
            float w = 0.f;
            if (vr) {
                if (role == 0) {
                    if (k < 10)      w = Whh0[tr * 10 + k];
                    else if (k < 12) w = Wih0[tr * 2 + (k - 10)];
                } else {
                    if (k < 10)      w = Wih1[tr * 10 + k];
                    else if (k < 20) w = Whh1[tr * 10 + (k - 10)];
                }
            }
            A[T][j] = (f16)(w * sc);
        }
#pragma unroll
        for (int q = 0; q < 4; ++q) {
            const int Rc = 16 * T + grp * 4 + q;
            const int uc = Rc >> 2, gc = Rc & 3;
            const float scc = (gc == 2) ? TANH_SCALE : SIG_SCALE;
            const int trc = gc * 10 + uc;
            float bb = 0.f;
            if (Rc < 40)
                bb = (role == 0) ? (bih0[trc] + bhh0[trc]) : (bih1[trc] + bhh1[trc]);
            bs[T][q] = bb * scc;
        }
    }

    // ---------- c state ----------
    const size_t cbase = (role == 0) ? 0 : (size_t)BATCH * 10;
    float cS[3];
#pragma unroll
    for (int T = 0; T < 3; ++T) {
        const int u = 4 * T + grp;
        cS[T] = (u < 10) ? c0in[cbase + b * 10 + u] : 0.f;
    }

    // ---------- LDS zero + state seed ----------
    {
        uint* p = (uint*)buf;                    // 3840 B = 960 uints
        for (int idx = tid; idx < 960; idx += 128) p[idx] = 0u;
    }
    __syncthreads();
    if (role == 0) {
        ushort* row = &buf[2][bl][0];            // read at iter 0
#pragma unroll
        for (int T = 0; T < 3; ++T) {
            const int u = 4 * T + grp;
            if (u < 10) { HU h; h.h = (f16)h0in[b * 10 + u]; row[u] = h.s; }
        }
    } else {
        ushort* row = &buf[0][bl][0];            // read at iter 1
#pragma unroll
        for (int T = 0; T < 3; ++T) {
            const int u = 4 * T + grp;
            if (u < 10) { HU h; h.h = (f16)h0in[(size_t)BATCH * 10 + b * 10 + u]; row[10 + u] = h.s; }
        }
    }

    // ---------- pointers & masks ----------
    const float* xq = x + b * 2 + (size_t)BATCH * 2;   // points at x(1)
    float2 xv = make_float2(0.f, 0.f);
    if (role == 0) xv = *reinterpret_cast<const float2*>(x + b * 2);  // x(0)
    ushort* yq = y + b * HID;

    const uint mx  = (grp < 2)  ? 0xFFFFFFFFu : 0u;
    const uint my0 = (grp == 0) ? 0xFFFFFFFFu : 0u;
    const uint sx  = (grp == 1) ? 0xFFFFFFFFu : 0u;

    auto body = [&](int i, ushort (*W)[40], const ushort (*Rb)[40]) {
        lds_barrier();
        if (role == 0) {
            if (i < SEQ) {
                const float2 xnext = *reinterpret_cast<const float2*>(xq);
                U4V r; r.u = *reinterpret_cast<const uint4*>(&Rb[bl][0] + grp * 8);
                UH2 xp; xp.p = __builtin_amdgcn_cvt_pkrtz(xv.x, xv.y);
                U4V bv;
                bv.u.x = r.u.x & mx;
                bv.u.y = (r.u.y & my0) | (xp.u & sx);
                bv.u.z = r.u.z & my0;
                bv.u.w = r.u.w & my0;

                const f32x4 d0 = __builtin_amdgcn_mfma_f32_16x16x32_f16(A[0], bv.v, bs[0], 0, 0, 0);
                const f32x4 d1 = __builtin_amdgcn_mfma_f32_16x16x32_f16(A[1], bv.v, bs[1], 0, 0, 0);
                const f32x4 d2 = __builtin_amdgcn_mfma_f32_16x16x32_f16(A[2], bv.v, bs[2], 0, 0, 0);

                HU hA; hA.h = (f16)lstm_unit(d0, cS[0]);
                HU hB; hB.h = (f16)lstm_unit(d1, cS[1]);
                HU hC; hC.h = (f16)lstm_unit(d2, cS[2]);

                ushort* wrow = &W[bl][0];
                wrow[grp]     = hA.s;
                wrow[4 + grp] = hB.s;
                if (grp < 2) wrow[8 + grp] = hC.s;

                xv = xnext;
                if (i + 2 < SEQ) xq += (size_t)BATCH * 2;
            }
        } else {
            if (i >= 1) {
                U4V r; r.u = *reinterpret_cast<const uint4*>(&Rb[bl][0] + grp * 8);

                const f32x4 d0 = __builtin_amdgcn_mfma_f32_16x16x32_f16(A[0], r.v, bs[0], 0, 0, 0);
                const f32x4 d1 = __builtin_amdgcn_mfma_f32_16x16x32_f16(A[1], r.v, bs[1], 0, 0, 0);
                const f32x4 d2 = __builtin_amdgcn_mfma_f32_16x16x32_f16(A[2], r.v, bs[2], 0, 0, 0);

                HU hA; hA.h = (f16)lstm_unit(d0, cS[0]);
                HU hB; hB.h = (f16)lstm_unit(d1, cS[1]);
                HU hC; hC.h = (f16)lstm_unit(d2, cS[2]);

                ushort* wrow = &W[bl][0];
                wrow[10 + grp] = hA.s;
                wrow[14 + grp] = hB.s;
                if (grp < 2) wrow[18 + grp] = hC.s;

                yq[grp]     = hA.s;
                yq[4 + grp] = hB.s;
                if (grp < 2) yq[8 + grp] = hC.s;
                yq += (size_t)BATCH * HID;
            }
        }
    };

    // 81 iterations = 27 exact mod-3 groups: (w,r) = (0,2),(1,0),(2,1)
    for (int i0 = 0; i0 < 81; i0 += 3) {
        body(i0 + 0, buf[0], buf[2]);
        body(i0 + 1, buf[1], buf[0]);
        body(i0 + 2, buf[2], buf[1]);
    }
}

// Head as MFMA GEMM over tanh(y), k-split across 2 waves per 16-row group —
// round-12 version verbatim (measured ~8 us).
__global__ __launch_bounds__(256, 2)
void head_mfma(const ushort* __restrict__ yflat, /* f16 bits of h1, [32768][800] */
               const float* __restrict__ W1, const float* __restrict__ b1,
               const float* __restrict__ W2, const float* __restrict__ b2,
               float* __restrict__ out) {
    __shared__ float sbuf[2][2][16][12];
    const int tid  = threadIdx.x;
    const int l    = tid & 63;
    const int wv   = tid >> 6;
    const int rg   = wv >> 1;      // row group 0,1
    const int half = wv & 1;       // k half 0,1
    const int bl   = l & 15;
    const int grp  = l >> 4;
    const long row = ((long)blockIdx.x * 2 + rg) * 16 + bl;

    const ushort* yrow = yflat + row * 800;
    const float* arow = W1 + (size_t)(bl < 10 ? bl : 9) * 800;

    const int c0 = half ? 13 : 0;
    const int c1 = half ? 25 : 13;

    f32x4 acc = {0.f, 0.f, 0.f, 0.f};
    for (int c = c0; c < c1; ++c) {
        U4V bv; bv.u = *reinterpret_cast<const uint4*>(yrow + c * 32 + grp * 8);
        f16x8 tv;
#pragma unroll
        for (int e = 0; e < 8; ++e)
            tv[e] = (f16)tanh_f((float)bv.v[e]);
        const float4 w0 = *reinterpret_cast<const float4*>(arow + c * 32 + grp * 8);
        const float4 w1 = *reinterpret_cast<const float4*>(arow + c * 32 + grp * 8 + 4);
        f16x8 af;
        af[0] = (f16)w0.x; af[1] = (f16)w0.y; af[2] = (f16)w0.z; af[3] = (f16)w0.w;
        af[4] = (f16)w1.x; af[5] = (f16)w1.y; af[6] = (f16)w1.z; af[7] = (f16)w1.w;
        acc = __builtin_amdgcn_mfma_f32_16x16x32_f16(af, tv, acc, 0, 0, 0);
    }

#pragma unroll
    for (int q = 0; q < 4; ++q) {
        const int o = grp * 4 + q;
        if (o < 10)
            sbuf[rg][half][bl][o] = acc[q];
    }
    __syncthreads();

    float s[10];
#pragma unroll
    for (int o = 0; o < 10; ++o)
        s[o] = sigp(SIG_SCALE * (sbuf[rg][0][bl][o] + sbuf[rg][1][bl][o] + b1[o]));

    // this wave emits outputs j = half*20 .. half*20+19; lane picks by grp
    const int jbase = half * 20 + (grp & 1) * 10;
    float* op = out + row * 40 + jbase;
#pragma unroll
    for (int jj = 0; jj < 10; ++jj) {
        const int j = jbase + jj;
        float r = b2[j];
#pragma unroll
        for (int o = 0; o < 10; ++o) r += s[o] * W2[j * 10 + o];
        op[jj] = r;
    }
}

extern "C" void kernel_launch(void* const* d_in, const int* in_sizes, int n_in,
                              void* d_out, int out_size, void* d_ws, size_t ws_size,
                              hipStream_t stream) {
    const float* x    = (const float*)d_in[0];
    const float* h0   = (const float*)d_in[1];
    const float* c0   = (const float*)d_in[2];
    const float* Wih0 = (const float*)d_in[3];
    const float* Whh0 = (const float*)d_in[4];
    const float* bih0 = (const float*)d_in[5];
    const float* bhh0 = (const float*)d_in[6];
    const float* Wih1 = (const float*)d_in[7];
    const float* Whh1 = (const float*)d_in[8];
    const float* bih1 = (const float*)d_in[9];
    const float* bhh1 = (const float*)d_in[10];
    const float* W1   = (const float*)d_in[11];
    const float* b1   = (const float*)d_in[12];
    const float* W2   = (const float*)d_in[13];
    const float* b2   = (const float*)d_in[14];
    float* out = (float*)d_out;
    ushort* yws = (ushort*)d_ws;  // f16 staging (raw h1), 80*32768*10*2 B

    // one batch-16 group per 128-thread block (L0 wave + L1 wave): 2048 blocks
    lstm2_spec<<<2048, 128, 0, stream>>>(x, h0, c0, Wih0, Whh0, bih0, bhh0,
                                         Wih1, Whh1, bih1, bhh1, yws);
    // 2 row-groups x 2 k-half waves per 256-thread block: 1024 blocks
    head_mfma<<<1024, 256, 0, stream>>>(yws, W1, b1, W2, b2, out);
}

// Round 15
// 88.563 us; speedup vs baseline: 1.2435x; 1.0574x over previous
//
#include <hip/hip_runtime.h>
#include <hip/hip_fp16.h>

#define SEQ   80
#define BATCH 32768
#define HID   10

typedef unsigned int uint;
typedef unsigned short ushort;
typedef _Float16 f16;
typedef __attribute__((ext_vector_type(8))) _Float16 f16x8;
typedef __attribute__((ext_vector_type(2))) _Float16 f16x2;
typedef __attribute__((ext_vector_type(2))) __fp16 fp16x2;
typedef __attribute__((ext_vector_type(4))) float f32x4;

#define SIG_SCALE  (-1.44269504f)
#define TANH_SCALE (-2.88539008f)

__device__ __forceinline__ float fast_rcp(float x)  { return __builtin_amdgcn_rcpf(x); }
__device__ __forceinline__ float fast_exp2(float x) { return __builtin_amdgcn_exp2f(x); }
__device__ __forceinline__ float sigp(float a)  { return fast_rcp(1.0f + fast_exp2(a)); }
__device__ __forceinline__ float tanhp(float a) { return 2.0f * fast_rcp(1.0f + fast_exp2(a)) - 1.0f; }
__device__ __forceinline__ float tanh_f(float x){ return tanhp(TANH_SCALE * x); }

union U4V { uint4 u; f16x8 v; };
union UH2 { uint u; f16x2 h; fp16x2 p; };
union HU  { f16 h; ushort s; };

// Single-rcp-merged LSTM cell: 5 exp2 + 2 rcp = 7 trans.
__device__ __forceinline__ float lstm_unit(const f32x4 d, float& c) {
    const float Ei = fast_exp2(d[0]);
    const float Ef = fast_exp2(d[1]);
    const float Eg = fast_exp2(d[2]);
    const float Eo = fast_exp2(d[3]);
    const float Pi = 1.0f + Ei, Pf = 1.0f + Ef, Pg = 1.0f + Eg;
    const float PiPg = Pi * Pg;
    const float R = fast_rcp(PiPg * Pf);
    c = c * (PiPg * R) + ((1.0f - Eg) * Pf) * R;
    const float Ec = fast_exp2(TANH_SCALE * c);
    const float R2 = fast_rcp((1.0f + Eo) * (1.0f + Ec));
    return (1.0f - Ec) * R2;
}

// Unified-B single-wave LSTM: ONE B operand per step feeds BOTH layers.
// B[k]: 0-9 = h0(i-1), 10-19 = h1(i-2), 20-21 = x(i), 22-31 = 0. All 80
// gate rows (40 L0 @ step i + 40 L1 @ step i-1, one-step lag) share it ->
// 5 MFMA tiles, ZERO garbage rows (r11 had 6 tiles incl. 8 pad rows), zero
// B-masking VALU (x lives in LDS; A is zero where a layer doesn't read).
// One wave per 16-batch group: no barriers; LDS write->read ordering is
// same-wave in-order. Boundary steps via predicated commit (lag intact).
__global__ __launch_bounds__(256, 2)
void lstm2_uni(const float* __restrict__ x, const float* __restrict__ h0in,
               const float* __restrict__ c0in,
               const float* __restrict__ Wih0, const float* __restrict__ Whh0,
               const float* __restrict__ bih0, const float* __restrict__ bhh0,
               const float* __restrict__ Wih1, const float* __restrict__ Whh1,
               const float* __restrict__ bih1, const float* __restrict__ bhh1,
               ushort* __restrict__ y /* f16 bits of h1 (pre-tanh), [T,B,H] */) {
    __shared__ __align__(16) ushort buf[4][16][40];
    const int tid = threadIdx.x;
    const int l   = tid & 63;
    const int wv  = tid >> 6;
    ushort (*B)[40] = buf[wv];
    const int bl  = l & 15;     // batch column
    const int grp = l >> 4;     // k/row group
    const long b  = ((long)blockIdx.x * 4 + wv) * 16 + bl;

    // ---------- A fragments (5 tiles, 80 rows), bias, c ----------
    f16x8 A[5];
    f32x4 bs[5];
    float cS[5];
#pragma unroll
    for (int T = 0; T < 5; ++T) {
        const int R = 16 * T + bl;              // A row 0..79
        const bool isL0 = (R < 40);
        const int rr = isL0 ? R : R - 40;
        const int u  = rr >> 2, gi = rr & 3;
        const int tr = gi * 10 + u;             // torch row (i|f|g|o chunks)
        const float sc = (gi == 2) ? TANH_SCALE : SIG_SCALE;
#pragma unroll
        for (int j = 0; j < 8; ++j) {
            const int k = grp * 8 + j;
            float w = 0.f;
            if (isL0) {
                if (k < 10)                 w = Whh0[tr * 10 + k];
                else if (k == 20 || k == 21) w = Wih0[tr * 2 + (k - 20)];
            } else {
                if (k < 10)      w = Wih1[tr * 10 + k];
                else if (k < 20) w = Whh1[tr * 10 + (k - 10)];
            }
            A[T][j] = (f16)(w * sc);
        }
#pragma unroll
        for (int q = 0; q < 4; ++q) {
            const int Rc = 16 * T + grp * 4 + q;   // D row this lane holds
            const bool l0 = (Rc < 40);
            const int rc = l0 ? Rc : Rc - 40;
            const int uc = rc >> 2, gc = rc & 3;
            const float scc = (gc == 2) ? TANH_SCALE : SIG_SCALE;
            const int trc = gc * 10 + uc;
            bs[T][q] = (l0 ? (bih0[trc] + bhh0[trc]) : (bih1[trc] + bhh1[trc])) * scc;
        }
        const int up = 4 * T + grp;             // this lane's unit id 0..19
        cS[T] = (up < 10) ? c0in[b * 10 + up]
                          : c0in[(size_t)BATCH * 10 + b * 10 + (up - 10)];
    }

    // ---------- LDS init: zero row tail, seed h0/h1/x(0) ----------
    {
        uint* p = (uint*)B;                      // 320 uints per group
#pragma unroll
        for (int i = 0; i < 5; ++i) p[l * 5 + i] = 0u;
    }
#pragma unroll
    for (int T = 0; T < 5; ++T) {
        const int up = 4 * T + grp;
        HU h;
        h.h = (up < 10) ? (f16)h0in[b * 10 + up]
                        : (f16)h0in[(size_t)BATCH * 10 + b * 10 + (up - 10)];
        B[bl][up] = h.s;
    }
    {
        const float2 x0 = *reinterpret_cast<const float2*>(x + b * 2);
        UH2 xp; xp.p = __builtin_amdgcn_cvt_pkrtz(x0.x, x0.y);
        if (grp == 0) *(uint*)&B[bl][20] = xp.u;
    }

    const float* xq = x + (size_t)BATCH * 2 + b * 2;   // x(1)
    ushort* yq = y + b * HID;                           // y(0) base

    for (int i = 0; i <= SEQ; ++i) {
        const bool doL0 = (i < SEQ);
        const bool doL1 = (i >= 1);

        // unified B read (raw b128, no masks)
        U4V r; r.u = *reinterpret_cast<const uint4*>(&B[bl][0] + grp * 8);
        // prefetch x(i+1) (clamped)
        const float2 xnext = *reinterpret_cast<const float2*>(xq);

        const f32x4 d0 = __builtin_amdgcn_mfma_f32_16x16x32_f16(A[0], r.v, bs[0], 0, 0, 0);
        const f32x4 d1 = __builtin_amdgcn_mfma_f32_16x16x32_f16(A[1], r.v, bs[1], 0, 0, 0);
        const f32x4 d2 = __builtin_amdgcn_mfma_f32_16x16x32_f16(A[2], r.v, bs[2], 0, 0, 0);
        const f32x4 d3 = __builtin_amdgcn_mfma_f32_16x16x32_f16(A[3], r.v, bs[3], 0, 0, 0);
        const f32x4 d4 = __builtin_amdgcn_mfma_f32_16x16x32_f16(A[4], r.v, bs[4], 0, 0, 0);

        // per-tile commit predicates: T=0,1 pure L0; T=3,4 pure L1; T=2 mixed
        const bool p2 = (grp < 2) ? doL0 : doL1;

        float c0n = cS[0], c1n = cS[1], c2n = cS[2], c3n = cS[3], c4n = cS[4];
        HU h0v; h0v.h = (f16)lstm_unit(d0, c0n);
        HU h1v; h1v.h = (f16)lstm_unit(d1, c1n);
        HU h2v; h2v.h = (f16)lstm_unit(d2, c2n);
        HU h3v; h3v.h = (f16)lstm_unit(d3, c3n);
        HU h4v; h4v.h = (f16)lstm_unit(d4, c4n);
        cS[0] = doL0 ? c0n : cS[0];
        cS[1] = doL0 ? c1n : cS[1];
        cS[2] = p2   ? c2n : cS[2];
        cS[3] = doL1 ? c3n : cS[3];
        cS[4] = doL1 ? c4n : cS[4];

        // h writes: slot = unit id (0-9 h0, 10-19 h1), row bl
        ushort* row = &B[bl][0];
        if (doL0) { row[grp] = h0v.s; row[4 + grp] = h1v.s; }
        if (p2)   { row[8 + grp] = h2v.s; }
        if (doL1) { row[12 + grp] = h3v.s; row[16 + grp] = h4v.s; }

        // x(i+1) into slots 20,21 for next body
        {
            UH2 xp; xp.p = __builtin_amdgcn_cvt_pkrtz(xnext.x, xnext.y);
            if (grp == 0) *(uint*)&B[bl][20] = xp.u;
        }

        // y stores: raw h1 f16 bits (tanh in head); units up>=10
        if (doL1) {
            if (grp >= 2) yq[8 + grp - 10 + 10 - 10] = h2v.s;   // up=8+grp -> u1=grp-2
            yq[2 + grp] = h3v.s;                                 // up=12+grp -> u1=2+grp
            yq[6 + grp] = h4v.s;                                 // up=16+grp -> u1=6+grp
            yq += (size_t)BATCH * HID;
        }

        if (i < SEQ - 2) xq += (size_t)BATCH * 2;
    }
}

// Head as MFMA GEMM over tanh(y), k-split across 2 waves per 16-row group —
// round-12 version verbatim (measured ~8 us).
__global__ __launch_bounds__(256, 2)
void head_mfma(const ushort* __restrict__ yflat, /* f16 bits of h1, [32768][800] */
               const float* __restrict__ W1, const float* __restrict__ b1,
               const float* __restrict__ W2, const float* __restrict__ b2,
               float* __restrict__ out) {
    __shared__ float sbuf[2][2][16][12];
    const int tid  = threadIdx.x;
    const int l    = tid & 63;
    const int wv   = tid >> 6;
    const int rg   = wv >> 1;      // row group 0,1
    const int half = wv & 1;       // k half 0,1
    const int bl   = l & 15;
    const int grp  = l >> 4;
    const long row = ((long)blockIdx.x * 2 + rg) * 16 + bl;

    const ushort* yrow = yflat + row * 800;
    const float* arow = W1 + (size_t)(bl < 10 ? bl : 9) * 800;

    const int c0 = half ? 13 : 0;
    const int c1 = half ? 25 : 13;

    f32x4 acc = {0.f, 0.f, 0.f, 0.f};
    for (int c = c0; c < c1; ++c) {
        U4V bv; bv.u = *reinterpret_cast<const uint4*>(yrow + c * 32 + grp * 8);
        f16x8 tv;
#pragma unroll
        for (int e = 0; e < 8; ++e)
            tv[e] = (f16)tanh_f((float)bv.v[e]);
        const float4 w0 = *reinterpret_cast<const float4*>(arow + c * 32 + grp * 8);
        const float4 w1 = *reinterpret_cast<const float4*>(arow + c * 32 + grp * 8 + 4);
        f16x8 af;
        af[0] = (f16)w0.x; af[1] = (f16)w0.y; af[2] = (f16)w0.z; af[3] = (f16)w0.w;
        af[4] = (f16)w1.x; af[5] = (f16)w1.y; af[6] = (f16)w1.z; af[7] = (f16)w1.w;
        acc = __builtin_amdgcn_mfma_f32_16x16x32_f16(af, tv, acc, 0, 0, 0);
    }

#pragma unroll
    for (int q = 0; q < 4; ++q) {
        const int o = grp * 4 + q;
        if (o < 10)
            sbuf[rg][half][bl][o] = acc[q];
    }
    __syncthreads();

    float s[10];
#pragma unroll
    for (int o = 0; o < 10; ++o)
        s[o] = sigp(SIG_SCALE * (sbuf[rg][0][bl][o] + sbuf[rg][1][bl][o] + b1[o]));

    const int jbase = half * 20 + (grp & 1) * 10;
    float* op = out + row * 40 + jbase;
#pragma unroll
    for (int jj = 0; jj < 10; ++jj) {
        const int j = jbase + jj;
        float r = b2[j];
#pragma unroll
        for (int o = 0; o < 10; ++o) r += s[o] * W2[j * 10 + o];
        op[jj] = r;
    }
}

extern "C" void kernel_launch(void* const* d_in, const int* in_sizes, int n_in,
                              void* d_out, int out_size, void* d_ws, size_t ws_size,
                              hipStream_t stream) {
    const float* x    = (const float*)d_in[0];
    const float* h0   = (const float*)d_in[1];
    const float* c0   = (const float*)d_in[2];
    const float* Wih0 = (const float*)d_in[3];
    const float* Whh0 = (const float*)d_in[4];
    const float* bih0 = (const float*)d_in[5];
    const float* bhh0 = (const float*)d_in[6];
    const float* Wih1 = (const float*)d_in[7];
    const float* Whh1 = (const float*)d_in[8];
    const float* bih1 = (const float*)d_in[9];
    const float* bhh1 = (const float*)d_in[10];
    const float* W1   = (const float*)d_in[11];
    const float* b1   = (const float*)d_in[12];
    const float* W2   = (const float*)d_in[13];
    const float* b2   = (const float*)d_in[14];
    float* out = (float*)d_out;
    ushort* yws = (ushort*)d_ws;  // f16 staging (raw h1), 80*32768*10*2 B

    // 4 batch-16 groups per 256-thread block (1 wave each, independent): 512 blocks
    lstm2_uni<<<512, 256, 0, stream>>>(x, h0, c0, Wih0, Whh0, bih0, bhh0,
                                       Wih1, Whh1, bih1, bhh1, yws);
    // 2 row-groups x 2 k-half waves per 256-thread block: 1024 blocks
    head_mfma<<<1024, 256, 0, stream>>>(yws, W1, b1, W2, b2, out);
}